// Round 7
// baseline (85.207 us; speedup 1.0000x reference)
//
#include <hip/hip_runtime.h>
#include <math.h>

#define S_LEN 2048
#define BATCH 4
#define DMODEL 1024
#define HDIM 64
#define NROWS (BATCH * S_LEN)   // 8192

typedef __attribute__((ext_vector_type(8))) short bf16x8;
typedef __attribute__((ext_vector_type(4))) float f32x4;

#define GLP(p) ((const __attribute__((address_space(1))) unsigned int*)(p))
#define LDP(p) ((__attribute__((address_space(3))) unsigned int*)(p))

__device__ inline ushort f2bf(float f) {
    union { float f; uint u; } v{f};
    uint r = v.u + 0x7fffu + ((v.u >> 16) & 1u);   // RNE
    return (ushort)(r >> 16);
}

__device__ inline bf16x8 cvt8(float4 a, float4 b) {
    bf16x8 r;
    r[0] = (short)f2bf(a.x); r[1] = (short)f2bf(a.y);
    r[2] = (short)f2bf(a.z); r[3] = (short)f2bf(a.w);
    r[4] = (short)f2bf(b.x); r[5] = (short)f2bf(b.y);
    r[6] = (short)f2bf(b.z); r[7] = (short)f2bf(b.w);
    return r;
}

// ---------------------------------------------------------------------------
// transpose_wh: w_h f32 [1024][64] -> whT bf16 [64][1024].  Grid (16, 3).
// ---------------------------------------------------------------------------
__global__ __launch_bounds__(256) void transpose_wh(
    const float* __restrict__ B0, const float* __restrict__ B1, const float* __restrict__ B2,
    ushort* __restrict__ T0, ushort* __restrict__ T1, ushort* __restrict__ T2)
{
    const int z = blockIdx.y;
    const float* B = (z == 0) ? B0 : (z == 1) ? B1 : B2;
    ushort* T      = (z == 0) ? T0 : (z == 1) ? T1 : T2;
    const int kr0 = blockIdx.x * 64;
    __shared__ ushort Ts[64][72];
    const int t = threadIdx.x;

    #pragma unroll
    for (int q = 0; q < 4; ++q) {
        int u   = t * 4 + q;
        int row = u >> 4;
        int c4  = (u & 15) << 2;
        float4 v = *reinterpret_cast<const float4*>(
            B + (size_t)(kr0 + row) * 64 + c4);
        Ts[row][c4 + 0] = f2bf(v.x); Ts[row][c4 + 1] = f2bf(v.y);
        Ts[row][c4 + 2] = f2bf(v.z); Ts[row][c4 + 3] = f2bf(v.w);
    }
    __syncthreads();
    #pragma unroll
    for (int q = 0; q < 2; ++q) {
        int u  = t * 2 + q;
        int h  = u >> 3;
        int k8 = (u & 7) << 3;
        uint4 o;
        uint* ow = reinterpret_cast<uint*>(&o);
        #pragma unroll
        for (int i = 0; i < 4; ++i)
            ow[i] = (uint)Ts[k8 + 2 * i][h] | ((uint)Ts[k8 + 2 * i + 1][h] << 16);
        *reinterpret_cast<uint4*>(T + (size_t)h * 1024 + kr0 + k8) = o;
    }
}

// ---------------------------------------------------------------------------
// Shared GEMM core (m97-style): C[M,64] = A_f32[M,1024] @ Wbf16T[64,1024]^T.
// Block = 32 rows, 4 waves: wave w -> rows 16*(w&1)+lc, col-pair (w>>1).
// A tile [32][64] f32 staged via global_load_lds (linear dest, XOR-swizzled
// source, 16B groups: LDS[row][g] = A[row][g^(row&7)]).  B-frags direct from
// global (L2-resident).  2 barriers/step; overlap via 3 blocks/CU.
// ---------------------------------------------------------------------------
#define GEMM_CORE(A, W, r0)                                                     \
    __shared__ __align__(16) float As[2048];                                    \
    const int t    = threadIdx.x;                                               \
    const int w    = t >> 6;                                                    \
    const int lane = t & 63;                                                    \
    const int lg   = lane >> 4;                                                 \
    const int lc   = lane & 15;                                                 \
    const int rowH  = (w & 1) << 4;                                             \
    const int npair = (w >> 1) << 1;                                            \
    const int idx0 = t * 4;                                                     \
    const int row0 = idx0 >> 6, g0 = (idx0 >> 2) & 15;                          \
    const int idx1 = idx0 + 1024;                                               \
    const int row1 = idx1 >> 6, g1 = (idx1 >> 2) & 15;                          \
    const float* s0 = A + (size_t)(r0 + row0) * 1024 + ((g0 ^ (row0 & 7)) << 2);\
    const float* s1 = A + (size_t)(r0 + row1) * 1024 + ((g1 ^ (row1 & 7)) << 2);\
    char* l0 = (char*)As + t * 16;                                              \
    char* l1 = (char*)As + t * 16 + 4096;                                       \
    const ushort* Wb0 = W + (size_t)(16 * npair + lc) * 1024 + lg * 8;          \
    const ushort* Wb1 = Wb0 + 16 * 1024;                                        \
    f32x4 acc[2] = {};                                                          \
    const int row  = rowH + lc;                                                 \
    const int base = row * 16;                                                  \
    const int rx   = lc & 7;                                                    \
    const float4* Af4 = reinterpret_cast<const float4*>(As);                    \
    for (int k0 = 0; k0 < 1024; k0 += 64) {                                     \
        __builtin_amdgcn_global_load_lds(GLP(s0 + k0), LDP(l0), 16, 0, 0);      \
        __builtin_amdgcn_global_load_lds(GLP(s1 + k0), LDP(l1), 16, 0, 0);      \
        uint4 b00 = *reinterpret_cast<const uint4*>(Wb0 + k0);                  \
        uint4 b01 = *reinterpret_cast<const uint4*>(Wb0 + k0 + 32);             \
        uint4 b10 = *reinterpret_cast<const uint4*>(Wb1 + k0);                  \
        uint4 b11 = *reinterpret_cast<const uint4*>(Wb1 + k0 + 32);             \
        __syncthreads();                                                        \
        float4 fa00 = Af4[base + ((lg * 2    ) ^ rx)];                          \
        float4 fa01 = Af4[base + ((lg * 2 + 1) ^ rx)];                          \
        float4 fa10 = Af4[base + ((lg * 2 + 8) ^ rx)];                          \
        float4 fa11 = Af4[base + ((lg * 2 + 9) ^ rx)];                          \
        bf16x8 a0 = cvt8(fa00, fa01);                                           \
        bf16x8 a1 = cvt8(fa10, fa11);                                           \
        acc[0] = __builtin_amdgcn_mfma_f32_16x16x32_bf16(                       \
            a0, __builtin_bit_cast(bf16x8, b00), acc[0], 0, 0, 0);              \
        acc[0] = __builtin_amdgcn_mfma_f32_16x16x32_bf16(                       \
            a1, __builtin_bit_cast(bf16x8, b01), acc[0], 0, 0, 0);              \
        acc[1] = __builtin_amdgcn_mfma_f32_16x16x32_bf16(                       \
            a0, __builtin_bit_cast(bf16x8, b10), acc[1], 0, 0, 0);              \
        acc[1] = __builtin_amdgcn_mfma_f32_16x16x32_bf16(                       \
            a1, __builtin_bit_cast(bf16x8, b11), acc[1], 0, 0, 0);              \
        __syncthreads();                                                        \
    }

// ---------------------------------------------------------------------------
// proj_gl: ph_z[8192,64] = bf16(x_z @ WeffT_z^T + bias).  Grid (256, 3).
// ---------------------------------------------------------------------------
__global__ __launch_bounds__(256) void proj_gl(
    const float* __restrict__ A0, const float* __restrict__ A1, const float* __restrict__ A2,
    const ushort* __restrict__ W0, const ushort* __restrict__ W1, const ushort* __restrict__ W2,
    const float* __restrict__ b0, const float* __restrict__ b1, const float* __restrict__ b2,
    ushort* __restrict__ O0, ushort* __restrict__ O1, ushort* __restrict__ O2)
{
    const int z = blockIdx.y;
    const float* A    = (z == 0) ? A0 : (z == 1) ? A1 : A2;
    const ushort* W   = (z == 0) ? W0 : (z == 1) ? W1 : W2;
    const float* bias = (z == 0) ? b0 : (z == 1) ? b1 : b2;
    ushort* O         = (z == 0) ? O0 : (z == 1) ? O1 : O2;
    const int r0 = blockIdx.x * 32;

    GEMM_CORE(A, W, r0)

    float bv0 = bias[16 * npair + lc];
    float bv1 = bias[16 * npair + 16 + lc];
    #pragma unroll
    for (int reg = 0; reg < 4; ++reg) {
        int orow = r0 + rowH + 4 * lg + reg;
        O[(size_t)orow * 64 + 16 * npair + lc]      = f2bf(acc[0][reg] + bv0);
        O[(size_t)orow * 64 + 16 * npair + 16 + lc] = f2bf(acc[1][reg] + bv1);
    }
}

// ---------------------------------------------------------------------------
// prep_gl: WeffT_z[h][d] = (W_z @ w_h_z)[d][h] bf16 (transposed store).
// Grid (32, 3).
// ---------------------------------------------------------------------------
__global__ __launch_bounds__(256) void prep_gl(
    const float* __restrict__ A0, const float* __restrict__ A1, const float* __restrict__ A2,
    const ushort* __restrict__ W0, const ushort* __restrict__ W1, const ushort* __restrict__ W2,
    ushort* __restrict__ T0, ushort* __restrict__ T1, ushort* __restrict__ T2)
{
    const int z = blockIdx.y;
    const float* A  = (z == 0) ? A0 : (z == 1) ? A1 : A2;
    const ushort* W = (z == 0) ? W0 : (z == 1) ? W1 : W2;
    ushort* T       = (z == 0) ? T0 : (z == 1) ? T1 : T2;
    const int r0 = blockIdx.x * 32;

    GEMM_CORE(A, W, r0)

    #pragma unroll
    for (int n = 0; n < 2; ++n)
        #pragma unroll
        for (int reg = 0; reg < 4; ++reg)
            T[(size_t)(16 * (npair + n) + lc) * 1024 + (r0 + rowH + 4 * lg + reg)] =
                f2bf(acc[n][reg]);
}

// ---------------------------------------------------------------------------
// Prep 2: WoT[e][j] = sum_h Wo[h*64+j][e]  -> bf16 [1024][64]
// ---------------------------------------------------------------------------
__global__ __launch_bounds__(256) void fold_wo(const float* __restrict__ Wo,
                                               ushort* __restrict__ WoT)
{
    int idx = blockIdx.x * 256 + threadIdx.x;
    int j = idx >> 10;
    int e = idx & 1023;
    float s = 0.f;
    #pragma unroll
    for (int h = 0; h < 16; ++h)
        s += Wo[(size_t)((h << 6) + j) * 1024 + e];
    WoT[(size_t)e * 64 + j] = f2bf(s);
}

// ---------------------------------------------------------------------------
// V transpose: vh[b][s][64] bf16 -> vhT[b][64][2048] bf16.  Grid (32, 4).
// ---------------------------------------------------------------------------
__global__ __launch_bounds__(256) void transpose_v(const ushort* __restrict__ vh,
                                                   ushort* __restrict__ vhT)
{
    const int b  = blockIdx.y;
    const int r0 = blockIdx.x * 64;
    __shared__ ushort T[64][72];
    const int t = threadIdx.x;

    #pragma unroll
    for (int q = 0; q < 2; ++q) {
        int u  = t * 2 + q;
        int s  = u >> 3;
        int d8 = (u & 7) << 3;
        uint4 v = *reinterpret_cast<const uint4*>(
            vh + ((size_t)b * S_LEN + r0 + s) * 64 + d8);
        *reinterpret_cast<uint4*>(&T[s][d8]) = v;
    }
    __syncthreads();
    #pragma unroll
    for (int q = 0; q < 2; ++q) {
        int u  = t * 2 + q;
        int d  = u >> 3;
        int s8 = (u & 7) << 3;
        uint4 o;
        uint* ow = reinterpret_cast<uint*>(&o);
        #pragma unroll
        for (int i = 0; i < 4; ++i)
            ow[i] = (uint)T[s8 + 2 * i][d] | ((uint)T[s8 + 2 * i + 1][d] << 16);
        *reinterpret_cast<uint4*>(
            vhT + (size_t)b * 64 * S_LEN + (size_t)d * S_LEN + r0 + s8) = o;
    }
}

// ---------------------------------------------------------------------------
// Flash attention (MFMA, split-KV): block = 64 q-rows x 256-kv chunk.
// Grid (144, 4).
// ---------------------------------------------------------------------------
__global__ __launch_bounds__(256) void flash_mfma(
    const ushort* __restrict__ qh, const ushort* __restrict__ kh,
    const ushort* __restrict__ vhT,
    float* __restrict__ Opart, float* __restrict__ mpart, float* __restrict__ lpart)
{
    const int b = blockIdx.y;
    const int u = blockIdx.x;
    int gi = 0;
    #pragma unroll
    for (int gg = 0; gg < 7; ++gg)
        if (u >= 2 * (gg + 1) * (gg + 2)) gi = gg + 1;
    const int rem = u - 2 * gi * (gi + 1);
    const int dq  = rem / (gi + 1);
    const int c   = rem - dq * (gi + 1);
    const int qt  = 4 * gi + dq;
    const int r0  = qt * 64;
    const int kvbase = c << 8;
    const int slot = b * 144 + u;

    __shared__ ushort Qs[64][72];
    __shared__ ushort Ks[64][72];
    __shared__ ushort Vt[64][72];
    __shared__ ushort Pw[4][16][72];

    const int t    = threadIdx.x;
    const int w    = t >> 6;
    const int lane = t & 63;
    const int lg   = lane >> 4;
    const int lc   = lane & 15;

    const ushort* qb  = qh  + (size_t)b * S_LEN * 64;
    const ushort* kb  = kh  + (size_t)b * S_LEN * 64;
    const ushort* vtb = vhT + (size_t)b * 64 * S_LEN;

    #pragma unroll
    for (int q = 0; q < 2; ++q) {
        int uu  = t * 2 + q;
        int row = uu >> 3;
        int c8  = (uu & 7) << 3;
        *reinterpret_cast<uint4*>(&Qs[row][c8]) =
            *reinterpret_cast<const uint4*>(qb + (size_t)(r0 + row) * 64 + c8);
    }
    __syncthreads();
    bf16x8 qf0 = *reinterpret_cast<const bf16x8*>(&Qs[16 * w + lc][lg * 8]);
    bf16x8 qf1 = *reinterpret_cast<const bf16x8*>(&Qs[16 * w + lc][32 + lg * 8]);

    f32x4 od[4] = {};
    float m = -INFINITY, lsum = 0.f;
    const int qrow = r0 + 16 * w + lc;

    const int ntt = min(4, ((r0 + 63 - kvbase) >> 6) + 1);
    for (int tt = 0; tt < ntt; ++tt) {
        const int t0 = kvbase + (tt << 6);
        __syncthreads();
        #pragma unroll
        for (int q = 0; q < 2; ++q) {
            int uu  = t * 2 + q;
            int row = uu >> 3;
            int c8  = (uu & 7) << 3;
            *reinterpret_cast<uint4*>(&Ks[row][c8]) =
                *reinterpret_cast<const uint4*>(kb + (size_t)(t0 + row) * 64 + c8);
            *reinterpret_cast<uint4*>(&Vt[row][c8]) =
                *reinterpret_cast<const uint4*>(vtb + (size_t)row * S_LEN + t0 + c8);
        }
        __syncthreads();

        if (t0 <= r0 + 16 * w + 15) {
            f32x4 s[4] = {};
            #pragma unroll
            for (int a = 0; a < 4; ++a) {
                bf16x8 kf0 = *reinterpret_cast<const bf16x8*>(&Ks[16 * a + lc][lg * 8]);
                bf16x8 kf1 = *reinterpret_cast<const bf16x8*>(&Ks[16 * a + lc][32 + lg * 8]);
                s[a] = __builtin_amdgcn_mfma_f32_16x16x32_bf16(kf0, qf0, s[a], 0, 0, 0);
                s[a] = __builtin_amdgcn_mfma_f32_16x16x32_bf16(kf1, qf1, s[a], 0, 0, 0);
            }
            float rm = -1e30f;
            #pragma unroll
            for (int a = 0; a < 4; ++a)
                #pragma unroll
                for (int reg = 0; reg < 4; ++reg) {
                    int kv = t0 + 16 * a + 4 * lg + reg;
                    float v = s[a][reg] * 0.125f;
                    if (kv > qrow) v = -1e30f;
                    s[a][reg] = v;
                    rm = fmaxf(rm, v);
                }
            rm = fmaxf(rm, __shfl_xor(rm, 16));
            rm = fmaxf(rm, __shfl_xor(rm, 32));
            float mn = fmaxf(m, rm);
            float sc = __expf(m - mn);
            float rs = 0.f;
            #pragma unroll
            for (int a = 0; a < 4; ++a)
                #pragma unroll
                for (int reg = 0; reg < 4; ++reg) {
                    float p = __expf(s[a][reg] - mn);
                    s[a][reg] = p;
                    rs += p;
                }
            rs += __shfl_xor(rs, 16);
            rs += __shfl_xor(rs, 32);
            lsum = lsum * sc + rs;
            m = mn;
            #pragma unroll
            for (int di = 0; di < 4; ++di) od[di] *= sc;

            #pragma unroll
            for (int a = 0; a < 4; ++a)
                #pragma unroll
                for (int rp = 0; rp < 2; ++rp) {
                    uint pk = (uint)f2bf(s[a][2 * rp]) |
                              ((uint)f2bf(s[a][2 * rp + 1]) << 16);
                    *reinterpret_cast<uint*>(&Pw[w][lc][16 * a + 4 * lg + 2 * rp]) = pk;
                }
            bf16x8 pf0 = *reinterpret_cast<const bf16x8*>(&Pw[w][lc][lg * 8]);
            bf16x8 pf1 = *reinterpret_cast<const bf16x8*>(&Pw[w][lc][32 + lg * 8]);
            #pragma unroll
            for (int di = 0; di < 4; ++di) {
                bf16x8 vf0 = *reinterpret_cast<const bf16x8*>(&Vt[16 * di + lc][lg * 8]);
                bf16x8 vf1 = *reinterpret_cast<const bf16x8*>(&Vt[16 * di + lc][32 + lg * 8]);
                od[di] = __builtin_amdgcn_mfma_f32_16x16x32_bf16(vf0, pf0, od[di], 0, 0, 0);
                od[di] = __builtin_amdgcn_mfma_f32_16x16x32_bf16(vf1, pf1, od[di], 0, 0, 0);
            }
        }
    }

    #pragma unroll
    for (int di = 0; di < 4; ++di)
        #pragma unroll
        for (int reg = 0; reg < 4; ++reg)
            Opart[(size_t)slot * 4096 + (16 * di + 4 * lg + reg) * 64 + 16 * w + lc] =
                od[di][reg];
    if (lg == 0) {
        mpart[slot * 64 + 16 * w + lc] = m;
        lpart[slot * 64 + 16 * w + lc] = lsum;
    }
}

// ---------------------------------------------------------------------------
// Combine partials -> oh bf16 [8192][64].  Grid (32, 4), 256 threads.
// ---------------------------------------------------------------------------
__global__ __launch_bounds__(256) void flash_combine(
    const float* __restrict__ Opart, const float* __restrict__ mpart,
    const float* __restrict__ lpart, ushort* __restrict__ oh)
{
    const int qt = blockIdx.x, b = blockIdx.y;
    const int gi = qt >> 2;
    const int nc = gi + 1;
    const int ubase = 2 * gi * (gi + 1) + (qt & 3) * (gi + 1);
    __shared__ float T[64][65];

    const int t  = threadIdx.x;
    const int q  = t & 63;
    const int d0 = (t >> 6) << 4;

    float mc[8];
    float M = -INFINITY;
    #pragma unroll
    for (int cc = 0; cc < 8; ++cc) {
        mc[cc] = (cc < nc) ? mpart[(b * 144 + ubase + cc) * 64 + q] : -INFINITY;
        M = fmaxf(M, mc[cc]);
    }
    float L = 0.f;
    float acc[16] = {};
    for (int cc = 0; cc < nc; ++cc) {
        const int slot = b * 144 + ubase + cc;
        float wgt = __expf(mc[cc] - M);
        L += lpart[slot * 64 + q] * wgt;
        const float* op = Opart + (size_t)slot * 4096 + q;
        #pragma unroll
        for (int i = 0; i < 16; ++i)
            acc[i] += wgt * op[(d0 + i) * 64];
    }
    float inv = 1.f / L;
    #pragma unroll
    for (int i = 0; i < 16; ++i) T[q][d0 + i] = acc[i] * inv;
    __syncthreads();

    const int q2 = t >> 2;
    const int ds = (t & 3) << 4;
    uint wbuf[8];
    #pragma unroll
    for (int i = 0; i < 8; ++i)
        wbuf[i] = (uint)f2bf(T[q2][ds + 2 * i]) |
                  ((uint)f2bf(T[q2][ds + 2 * i + 1]) << 16);
    ushort* dst = oh + ((size_t)b * S_LEN + qt * 64 + q2) * 64 + ds;
    uint4 o1, o2;
    o1.x = wbuf[0]; o1.y = wbuf[1]; o1.z = wbuf[2]; o1.w = wbuf[3];
    o2.x = wbuf[4]; o2.y = wbuf[5]; o2.z = wbuf[6]; o2.w = wbuf[7];
    *reinterpret_cast<uint4*>(dst)     = o1;
    *reinterpret_cast<uint4*>(dst + 8) = o2;
}

// ---------------------------------------------------------------------------
// Epilogue (MFMA): out[8192,1024] = oh[8192,64] @ WoT^T.  Grid (128, 8).
// ---------------------------------------------------------------------------
__global__ __launch_bounds__(256) void epilogue_mfma(
    const ushort* __restrict__ oh, const ushort* __restrict__ WoT,
    float* __restrict__ out)
{
    const int r0 = blockIdx.x * 64;
    const int c0 = blockIdx.y * 128;
    __shared__ ushort As[64][72];
    __shared__ ushort Bs[128][72];

    const int t    = threadIdx.x;
    const int w    = t >> 6;
    const int lane = t & 63;
    const int lg   = lane >> 4;
    const int lc   = lane & 15;

    #pragma unroll
    for (int q = 0; q < 2; ++q) {
        int u   = t * 2 + q;
        int row = u >> 3;
        int c8  = (u & 7) << 3;
        *reinterpret_cast<uint4*>(&As[row][c8]) =
            *reinterpret_cast<const uint4*>(oh + (size_t)(r0 + row) * 64 + c8);
    }
    #pragma unroll
    for (int q = 0; q < 4; ++q) {
        int u   = t * 4 + q;
        int row = u >> 3;
        int c8  = (u & 7) << 3;
        *reinterpret_cast<uint4*>(&Bs[row][c8]) =
            *reinterpret_cast<const uint4*>(WoT + (size_t)(c0 + row) * 64 + c8);
    }
    __syncthreads();

    bf16x8 af0 = *reinterpret_cast<const bf16x8*>(&As[16 * w + lc][lg * 8]);
    bf16x8 af1 = *reinterpret_cast<const bf16x8*>(&As[16 * w + lc][32 + lg * 8]);
    f32x4 acc[8] = {};
    #pragma unroll
    for (int n = 0; n < 8; ++n) {
        bf16x8 bf0 = *reinterpret_cast<const bf16x8*>(&Bs[16 * n + lc][lg * 8]);
        bf16x8 bf1 = *reinterpret_cast<const bf16x8*>(&Bs[16 * n + lc][32 + lg * 8]);
        acc[n] = __builtin_amdgcn_mfma_f32_16x16x32_bf16(af0, bf0, acc[n], 0, 0, 0);
        acc[n] = __builtin_amdgcn_mfma_f32_16x16x32_bf16(af1, bf1, acc[n], 0, 0, 0);
    }
    #pragma unroll
    for (int n = 0; n < 8; ++n)
        #pragma unroll
        for (int reg = 0; reg < 4; ++reg)
            out[(size_t)(r0 + 16 * w + 4 * lg + reg) * 1024 + c0 + 16 * n + lc] =
                acc[n][reg];
}

// ---------------------------------------------------------------------------
extern "C" void kernel_launch(void* const* d_in, const int* in_sizes, int n_in,
                              void* d_out, int out_size, void* d_ws, size_t ws_size,
                              hipStream_t stream)
{
    const float* query = (const float*)d_in[0];
    const float* key   = (const float*)d_in[1];
    const float* value = (const float*)d_in[2];
    const float* Wq   = (const float*)d_in[4];
    const float* Wk   = (const float*)d_in[5];
    const float* Wv   = (const float*)d_in[6];
    const float* wq_h = (const float*)d_in[7];
    const float* bq_h = (const float*)d_in[8];
    const float* wk_h = (const float*)d_in[9];
    const float* bk_h = (const float*)d_in[10];
    const float* wv_h = (const float*)d_in[11];
    const float* bv_h = (const float*)d_in[12];
    const float* Wo   = (const float*)d_in[13];
    float* out = (float*)d_out;

    // workspace (ushort units): ~6.2 MB
    ushort* W16  = (ushort*)d_ws;
    ushort* WT0  = W16;                 // 64*1024 each
    ushort* WT1  = W16 + 65536;
    ushort* WT2  = W16 + 131072;
    ushort* WoT  = W16 + 196608;        // 1024*64
    ushort* qh   = W16 + 262144;        // 8192*64 each
    ushort* kh   = qh + 524288;
    ushort* vh   = kh + 524288;
    ushort* vhT  = vh + 524288;
    ushort* oh   = vhT + 524288;
    ushort* whT0 = oh + 524288;         // 64*1024 each
    ushort* whT1 = whT0 + 65536;
    ushort* whT2 = whT1 + 65536;

    // flash partials in d_out (9.7 MB < 33.5 MB); epilogue rewrites all of it.
    float* Opart = out;                 // 576 * 4096
    float* mpart = out + 2359296;       // 576 * 64
    float* lpart = out + 2396160;

    transpose_wh<<<dim3(16, 3), 256, 0, stream>>>(
        wq_h, wk_h, wv_h, whT0, whT1, whT2);
    fold_wo<<<256, 256, 0, stream>>>(Wo, WoT);

    prep_gl<<<dim3(32, 3), 256, 0, stream>>>(
        Wq, Wk, Wv, whT0, whT1, whT2, WT0, WT1, WT2);

    proj_gl<<<dim3(256, 3), 256, 0, stream>>>(
        query, key, value, WT0, WT1, WT2, bq_h, bk_h, bv_h, qh, kh, vh);

    transpose_v<<<dim3(S_LEN / 64, BATCH), 256, 0, stream>>>(vh, vhT);

    flash_mfma<<<dim3(144, BATCH), 256, 0, stream>>>(
        qh, kh, vhT, Opart, mpart, lpart);
    flash_combine<<<dim3(S_LEN / 64, BATCH), 256, 0, stream>>>(
        Opart, mpart, lpart, oh);

    epilogue_mfma<<<dim3(NROWS / 64, DMODEL / 128), 256, 0, stream>>>(oh, WoT, out);
}

// Round 8
// 83.564 us; speedup vs baseline: 1.0197x; 1.0197x over previous
//
#include <hip/hip_runtime.h>
#include <math.h>

#define S_LEN 2048
#define BATCH 4
#define DMODEL 1024
#define HDIM 64
#define NROWS (BATCH * S_LEN)   // 8192

typedef __attribute__((ext_vector_type(8))) short bf16x8;
typedef __attribute__((ext_vector_type(4))) float f32x4;

__device__ inline ushort f2bf(float f) {
    union { float f; uint u; } v{f};
    uint r = v.u + 0x7fffu + ((v.u >> 16) & 1u);   // RNE
    return (ushort)(r >> 16);
}

__device__ inline bf16x8 cvt8(float4 a, float4 b) {
    bf16x8 r;
    r[0] = (short)f2bf(a.x); r[1] = (short)f2bf(a.y);
    r[2] = (short)f2bf(a.z); r[3] = (short)f2bf(a.w);
    r[4] = (short)f2bf(b.x); r[5] = (short)f2bf(b.y);
    r[6] = (short)f2bf(b.z); r[7] = (short)f2bf(b.w);
    return r;
}

// ---------------------------------------------------------------------------
// transpose_wh: w_h f32 [1024][64] -> whT bf16 [64][1024].  Grid (16, 3).
// ---------------------------------------------------------------------------
__global__ __launch_bounds__(256) void transpose_wh(
    const float* __restrict__ B0, const float* __restrict__ B1, const float* __restrict__ B2,
    ushort* __restrict__ T0, ushort* __restrict__ T1, ushort* __restrict__ T2)
{
    const int z = blockIdx.y;
    const float* B = (z == 0) ? B0 : (z == 1) ? B1 : B2;
    ushort* T      = (z == 0) ? T0 : (z == 1) ? T1 : T2;
    const int kr0 = blockIdx.x * 64;
    __shared__ ushort Ts[64][72];
    const int t = threadIdx.x;

    #pragma unroll
    for (int q = 0; q < 4; ++q) {
        int u   = t * 4 + q;
        int row = u >> 4;
        int c4  = (u & 15) << 2;
        float4 v = *reinterpret_cast<const float4*>(
            B + (size_t)(kr0 + row) * 64 + c4);
        Ts[row][c4 + 0] = f2bf(v.x); Ts[row][c4 + 1] = f2bf(v.y);
        Ts[row][c4 + 2] = f2bf(v.z); Ts[row][c4 + 3] = f2bf(v.w);
    }
    __syncthreads();
    #pragma unroll
    for (int q = 0; q < 2; ++q) {
        int u  = t * 2 + q;
        int h  = u >> 3;
        int k8 = (u & 7) << 3;
        uint4 o;
        uint* ow = reinterpret_cast<uint*>(&o);
        #pragma unroll
        for (int i = 0; i < 4; ++i)
            ow[i] = (uint)Ts[k8 + 2 * i][h] | ((uint)Ts[k8 + 2 * i + 1][h] << 16);
        *reinterpret_cast<uint4*>(T + (size_t)h * 1024 + kr0 + k8) = o;
    }
}

// ---------------------------------------------------------------------------
// prep_direct: WeffT_z[h][d] = (W_z @ w_h_z)^T bf16.  Grid (64, 3), 256 thr.
// Block = 16 W-rows; wave w covers k in [256w, 256w+256). Direct-from-global
// MFMA fragments (no LDS staging, no K-loop barriers); LDS cross-wave reduce.
// NO min-waves clamp: prefetch registers must stay live (round-6 lesson).
// ---------------------------------------------------------------------------
__global__ __launch_bounds__(256) void prep_direct(
    const float* __restrict__ A0, const float* __restrict__ A1, const float* __restrict__ A2,
    const ushort* __restrict__ W0, const ushort* __restrict__ W1, const ushort* __restrict__ W2,
    ushort* __restrict__ T0, ushort* __restrict__ T1, ushort* __restrict__ T2)
{
    const int z = blockIdx.y;
    const float* A  = (z == 0) ? A0 : (z == 1) ? A1 : A2;
    const ushort* W = (z == 0) ? W0 : (z == 1) ? W1 : W2;
    ushort* T       = (z == 0) ? T0 : (z == 1) ? T1 : T2;

    __shared__ float Pr[4][16][64];   // 16 KB

    const int t    = threadIdx.x;
    const int w    = t >> 6;
    const int lane = t & 63;
    const int lg   = lane >> 4;
    const int lc   = lane & 15;
    const int r0   = blockIdx.x * 16;

    const float*  Ap = A + (size_t)(r0 + lc) * 1024 + (w << 8) + (lg << 3);
    const ushort* Bp = W + (size_t)lc * 1024 + (w << 8) + (lg << 3);

    f32x4 acc[4] = {};
    float4 a0[2], a1[2];
    uint4  bl[2][4];

    #pragma unroll
    for (int d = 0; d < 2; ++d) {
        a0[d] = *reinterpret_cast<const float4*>(Ap + d * 32);
        a1[d] = *reinterpret_cast<const float4*>(Ap + d * 32 + 4);
        #pragma unroll
        for (int n = 0; n < 4; ++n)
            bl[d][n] = *reinterpret_cast<const uint4*>(Bp + n * 16384 + d * 32);
    }

    #pragma unroll
    for (int ks = 0; ks < 8; ++ks) {
        const int d = ks & 1;
        bf16x8 af = cvt8(a0[d], a1[d]);
        bf16x8 bfr[4];
        #pragma unroll
        for (int n = 0; n < 4; ++n)
            bfr[n] = __builtin_bit_cast(bf16x8, bl[d][n]);
        if (ks < 6) {
            a0[d] = *reinterpret_cast<const float4*>(Ap + (ks + 2) * 32);
            a1[d] = *reinterpret_cast<const float4*>(Ap + (ks + 2) * 32 + 4);
            #pragma unroll
            for (int n = 0; n < 4; ++n)
                bl[d][n] = *reinterpret_cast<const uint4*>(Bp + n * 16384 + (ks + 2) * 32);
        }
        #pragma unroll
        for (int n = 0; n < 4; ++n)
            acc[n] = __builtin_amdgcn_mfma_f32_16x16x32_bf16(af, bfr[n], acc[n], 0, 0, 0);
    }

    #pragma unroll
    for (int n = 0; n < 4; ++n)
        #pragma unroll
        for (int reg = 0; reg < 4; ++reg)
            Pr[w][4 * lg + reg][16 * n + lc] = acc[n][reg];
    __syncthreads();

    const int row = t >> 4;          // 0..15
    const int col = (t & 15) << 2;   // 0..60
    float s[4];
    #pragma unroll
    for (int i = 0; i < 4; ++i)
        s[i] = Pr[0][row][col + i] + Pr[1][row][col + i] +
               Pr[2][row][col + i] + Pr[3][row][col + i];
    #pragma unroll
    for (int i = 0; i < 4; ++i)
        T[(size_t)(col + i) * 1024 + r0 + row] = f2bf(s[i]);
}

// ---------------------------------------------------------------------------
// proj_direct: ph_z[8192,64] = bf16(x_z @ WeffT_z^T + bias).  Grid (512, 3).
// Same barrier-free structure.  NO min-waves clamp.
// ---------------------------------------------------------------------------
__global__ __launch_bounds__(256) void proj_direct(
    const float* __restrict__ A0, const float* __restrict__ A1, const float* __restrict__ A2,
    const ushort* __restrict__ W0, const ushort* __restrict__ W1, const ushort* __restrict__ W2,
    const float* __restrict__ b0, const float* __restrict__ b1, const float* __restrict__ b2,
    ushort* __restrict__ O0, ushort* __restrict__ O1, ushort* __restrict__ O2)
{
    const int z = blockIdx.y;
    const float* A    = (z == 0) ? A0 : (z == 1) ? A1 : A2;
    const ushort* W   = (z == 0) ? W0 : (z == 1) ? W1 : W2;
    const float* bias = (z == 0) ? b0 : (z == 1) ? b1 : b2;
    ushort* O         = (z == 0) ? O0 : (z == 1) ? O1 : O2;

    __shared__ float Pr[4][16][64];   // 16 KB

    const int t    = threadIdx.x;
    const int w    = t >> 6;
    const int lane = t & 63;
    const int lg   = lane >> 4;
    const int lc   = lane & 15;
    const int r0   = blockIdx.x * 16;

    const float*  Ap = A + (size_t)(r0 + lc) * 1024 + (w << 8) + (lg << 3);
    const ushort* Bp = W + (size_t)lc * 1024 + (w << 8) + (lg << 3);

    f32x4 acc[4] = {};
    float4 a0[2], a1[2];
    uint4  bl[2][4];

    #pragma unroll
    for (int d = 0; d < 2; ++d) {
        a0[d] = *reinterpret_cast<const float4*>(Ap + d * 32);
        a1[d] = *reinterpret_cast<const float4*>(Ap + d * 32 + 4);
        #pragma unroll
        for (int n = 0; n < 4; ++n)
            bl[d][n] = *reinterpret_cast<const uint4*>(Bp + n * 16384 + d * 32);
    }

    #pragma unroll
    for (int ks = 0; ks < 8; ++ks) {
        const int d = ks & 1;
        bf16x8 af = cvt8(a0[d], a1[d]);
        bf16x8 bfr[4];
        #pragma unroll
        for (int n = 0; n < 4; ++n)
            bfr[n] = __builtin_bit_cast(bf16x8, bl[d][n]);
        if (ks < 6) {
            a0[d] = *reinterpret_cast<const float4*>(Ap + (ks + 2) * 32);
            a1[d] = *reinterpret_cast<const float4*>(Ap + (ks + 2) * 32 + 4);
            #pragma unroll
            for (int n = 0; n < 4; ++n)
                bl[d][n] = *reinterpret_cast<const uint4*>(Bp + n * 16384 + (ks + 2) * 32);
        }
        #pragma unroll
        for (int n = 0; n < 4; ++n)
            acc[n] = __builtin_amdgcn_mfma_f32_16x16x32_bf16(af, bfr[n], acc[n], 0, 0, 0);
    }

    #pragma unroll
    for (int n = 0; n < 4; ++n)
        #pragma unroll
        for (int reg = 0; reg < 4; ++reg)
            Pr[w][4 * lg + reg][16 * n + lc] = acc[n][reg];
    __syncthreads();

    const int row = t >> 4;
    const int col = (t & 15) << 2;
    float4 bb = *reinterpret_cast<const float4*>(bias + col);
    float s0 = Pr[0][row][col + 0] + Pr[1][row][col + 0] + Pr[2][row][col + 0] + Pr[3][row][col + 0] + bb.x;
    float s1 = Pr[0][row][col + 1] + Pr[1][row][col + 1] + Pr[2][row][col + 1] + Pr[3][row][col + 1] + bb.y;
    float s2 = Pr[0][row][col + 2] + Pr[1][row][col + 2] + Pr[2][row][col + 2] + Pr[3][row][col + 2] + bb.z;
    float s3 = Pr[0][row][col + 3] + Pr[1][row][col + 3] + Pr[2][row][col + 3] + Pr[3][row][col + 3] + bb.w;
    ushort4 o;
    o.x = f2bf(s0); o.y = f2bf(s1); o.z = f2bf(s2); o.w = f2bf(s3);
    *reinterpret_cast<ushort4*>(O + (size_t)(r0 + row) * 64 + col) = o;
}

// ---------------------------------------------------------------------------
// Prep 2: WoT[e][j] = sum_h Wo[h*64+j][e]  -> bf16 [1024][64]
// ---------------------------------------------------------------------------
__global__ __launch_bounds__(256) void fold_wo(const float* __restrict__ Wo,
                                               ushort* __restrict__ WoT)
{
    int idx = blockIdx.x * 256 + threadIdx.x;
    int j = idx >> 10;
    int e = idx & 1023;
    float s = 0.f;
    #pragma unroll
    for (int h = 0; h < 16; ++h)
        s += Wo[(size_t)((h << 6) + j) * 1024 + e];
    WoT[(size_t)e * 64 + j] = f2bf(s);
}

// ---------------------------------------------------------------------------
// V transpose: vh[b][s][64] bf16 -> vhT[b][64][2048] bf16.  Grid (32, 4).
// ---------------------------------------------------------------------------
__global__ __launch_bounds__(256) void transpose_v(const ushort* __restrict__ vh,
                                                   ushort* __restrict__ vhT)
{
    const int b  = blockIdx.y;
    const int r0 = blockIdx.x * 64;
    __shared__ ushort T[64][72];
    const int t = threadIdx.x;

    #pragma unroll
    for (int q = 0; q < 2; ++q) {
        int u  = t * 2 + q;
        int s  = u >> 3;
        int d8 = (u & 7) << 3;
        uint4 v = *reinterpret_cast<const uint4*>(
            vh + ((size_t)b * S_LEN + r0 + s) * 64 + d8);
        *reinterpret_cast<uint4*>(&T[s][d8]) = v;
    }
    __syncthreads();
    #pragma unroll
    for (int q = 0; q < 2; ++q) {
        int u  = t * 2 + q;
        int d  = u >> 3;
        int s8 = (u & 7) << 3;
        uint4 o;
        uint* ow = reinterpret_cast<uint*>(&o);
        #pragma unroll
        for (int i = 0; i < 4; ++i)
            ow[i] = (uint)T[s8 + 2 * i][d] | ((uint)T[s8 + 2 * i + 1][d] << 16);
        *reinterpret_cast<uint4*>(
            vhT + (size_t)b * 64 * S_LEN + (size_t)d * S_LEN + r0 + s8) = o;
    }
}

// ---------------------------------------------------------------------------
// Flash attention (MFMA, split-KV): block = 64 q-rows x 256-kv chunk.
// Grid (144, 4).
// ---------------------------------------------------------------------------
__global__ __launch_bounds__(256) void flash_mfma(
    const ushort* __restrict__ qh, const ushort* __restrict__ kh,
    const ushort* __restrict__ vhT,
    float* __restrict__ Opart, float* __restrict__ mpart, float* __restrict__ lpart)
{
    const int b = blockIdx.y;
    const int u = blockIdx.x;
    int gi = 0;
    #pragma unroll
    for (int gg = 0; gg < 7; ++gg)
        if (u >= 2 * (gg + 1) * (gg + 2)) gi = gg + 1;
    const int rem = u - 2 * gi * (gi + 1);
    const int dq  = rem / (gi + 1);
    const int c   = rem - dq * (gi + 1);
    const int qt  = 4 * gi + dq;
    const int r0  = qt * 64;
    const int kvbase = c << 8;
    const int slot = b * 144 + u;

    __shared__ ushort Qs[64][72];
    __shared__ ushort Ks[64][72];
    __shared__ ushort Vt[64][72];
    __shared__ ushort Pw[4][16][72];

    const int t    = threadIdx.x;
    const int w    = t >> 6;
    const int lane = t & 63;
    const int lg   = lane >> 4;
    const int lc   = lane & 15;

    const ushort* qb  = qh  + (size_t)b * S_LEN * 64;
    const ushort* kb  = kh  + (size_t)b * S_LEN * 64;
    const ushort* vtb = vhT + (size_t)b * 64 * S_LEN;

    #pragma unroll
    for (int q = 0; q < 2; ++q) {
        int uu  = t * 2 + q;
        int row = uu >> 3;
        int c8  = (uu & 7) << 3;
        *reinterpret_cast<uint4*>(&Qs[row][c8]) =
            *reinterpret_cast<const uint4*>(qb + (size_t)(r0 + row) * 64 + c8);
    }
    __syncthreads();
    bf16x8 qf0 = *reinterpret_cast<const bf16x8*>(&Qs[16 * w + lc][lg * 8]);
    bf16x8 qf1 = *reinterpret_cast<const bf16x8*>(&Qs[16 * w + lc][32 + lg * 8]);

    f32x4 od[4] = {};
    float m = -INFINITY, lsum = 0.f;
    const int qrow = r0 + 16 * w + lc;

    const int ntt = min(4, ((r0 + 63 - kvbase) >> 6) + 1);
    for (int tt = 0; tt < ntt; ++tt) {
        const int t0 = kvbase + (tt << 6);
        __syncthreads();
        #pragma unroll
        for (int q = 0; q < 2; ++q) {
            int uu  = t * 2 + q;
            int row = uu >> 3;
            int c8  = (uu & 7) << 3;
            *reinterpret_cast<uint4*>(&Ks[row][c8]) =
                *reinterpret_cast<const uint4*>(kb + (size_t)(t0 + row) * 64 + c8);
            *reinterpret_cast<uint4*>(&Vt[row][c8]) =
                *reinterpret_cast<const uint4*>(vtb + (size_t)row * S_LEN + t0 + c8);
        }
        __syncthreads();

        if (t0 <= r0 + 16 * w + 15) {
            f32x4 s[4] = {};
            #pragma unroll
            for (int a = 0; a < 4; ++a) {
                bf16x8 kf0 = *reinterpret_cast<const bf16x8*>(&Ks[16 * a + lc][lg * 8]);
                bf16x8 kf1 = *reinterpret_cast<const bf16x8*>(&Ks[16 * a + lc][32 + lg * 8]);
                s[a] = __builtin_amdgcn_mfma_f32_16x16x32_bf16(kf0, qf0, s[a], 0, 0, 0);
                s[a] = __builtin_amdgcn_mfma_f32_16x16x32_bf16(kf1, qf1, s[a], 0, 0, 0);
            }
            float rm = -1e30f;
            #pragma unroll
            for (int a = 0; a < 4; ++a)
                #pragma unroll
                for (int reg = 0; reg < 4; ++reg) {
                    int kv = t0 + 16 * a + 4 * lg + reg;
                    float v = s[a][reg] * 0.125f;
                    if (kv > qrow) v = -1e30f;
                    s[a][reg] = v;
                    rm = fmaxf(rm, v);
                }
            rm = fmaxf(rm, __shfl_xor(rm, 16));
            rm = fmaxf(rm, __shfl_xor(rm, 32));
            float mn = fmaxf(m, rm);
            float sc = __expf(m - mn);
            float rs = 0.f;
            #pragma unroll
            for (int a = 0; a < 4; ++a)
                #pragma unroll
                for (int reg = 0; reg < 4; ++reg) {
                    float p = __expf(s[a][reg] - mn);
                    s[a][reg] = p;
                    rs += p;
                }
            rs += __shfl_xor(rs, 16);
            rs += __shfl_xor(rs, 32);
            lsum = lsum * sc + rs;
            m = mn;
            #pragma unroll
            for (int di = 0; di < 4; ++di) od[di] *= sc;

            #pragma unroll
            for (int a = 0; a < 4; ++a)
                #pragma unroll
                for (int rp = 0; rp < 2; ++rp) {
                    uint pk = (uint)f2bf(s[a][2 * rp]) |
                              ((uint)f2bf(s[a][2 * rp + 1]) << 16);
                    *reinterpret_cast<uint*>(&Pw[w][lc][16 * a + 4 * lg + 2 * rp]) = pk;
                }
            bf16x8 pf0 = *reinterpret_cast<const bf16x8*>(&Pw[w][lc][lg * 8]);
            bf16x8 pf1 = *reinterpret_cast<const bf16x8*>(&Pw[w][lc][32 + lg * 8]);
            #pragma unroll
            for (int di = 0; di < 4; ++di) {
                bf16x8 vf0 = *reinterpret_cast<const bf16x8*>(&Vt[16 * di + lc][lg * 8]);
                bf16x8 vf1 = *reinterpret_cast<const bf16x8*>(&Vt[16 * di + lc][32 + lg * 8]);
                od[di] = __builtin_amdgcn_mfma_f32_16x16x32_bf16(vf0, pf0, od[di], 0, 0, 0);
                od[di] = __builtin_amdgcn_mfma_f32_16x16x32_bf16(vf1, pf1, od[di], 0, 0, 0);
            }
        }
    }

    #pragma unroll
    for (int di = 0; di < 4; ++di)
        #pragma unroll
        for (int reg = 0; reg < 4; ++reg)
            Opart[(size_t)slot * 4096 + (16 * di + 4 * lg + reg) * 64 + 16 * w + lc] =
                od[di][reg];
    if (lg == 0) {
        mpart[slot * 64 + 16 * w + lc] = m;
        lpart[slot * 64 + 16 * w + lc] = lsum;
    }
}

// ---------------------------------------------------------------------------
// Combine partials -> oh bf16 [8192][64].  Grid (32, 4), 256 threads.
// ---------------------------------------------------------------------------
__global__ __launch_bounds__(256) void flash_combine(
    const float* __restrict__ Opart, const float* __restrict__ mpart,
    const float* __restrict__ lpart, ushort* __restrict__ oh)
{
    const int qt = blockIdx.x, b = blockIdx.y;
    const int gi = qt >> 2;
    const int nc = gi + 1;
    const int ubase = 2 * gi * (gi + 1) + (qt & 3) * (gi + 1);
    __shared__ float T[64][65];

    const int t  = threadIdx.x;
    const int q  = t & 63;
    const int d0 = (t >> 6) << 4;

    float mc[8];
    float M = -INFINITY;
    #pragma unroll
    for (int cc = 0; cc < 8; ++cc) {
        mc[cc] = (cc < nc) ? mpart[(b * 144 + ubase + cc) * 64 + q] : -INFINITY;
        M = fmaxf(M, mc[cc]);
    }
    float L = 0.f;
    float acc[16] = {};
    for (int cc = 0; cc < nc; ++cc) {
        const int slot = b * 144 + ubase + cc;
        float wgt = __expf(mc[cc] - M);
        L += lpart[slot * 64 + q] * wgt;
        const float* op = Opart + (size_t)slot * 4096 + q;
        #pragma unroll
        for (int i = 0; i < 16; ++i)
            acc[i] += wgt * op[(d0 + i) * 64];
    }
    float inv = 1.f / L;
    #pragma unroll
    for (int i = 0; i < 16; ++i) T[q][d0 + i] = acc[i] * inv;
    __syncthreads();

    const int q2 = t >> 2;
    const int ds = (t & 3) << 4;
    uint wbuf[8];
    #pragma unroll
    for (int i = 0; i < 8; ++i)
        wbuf[i] = (uint)f2bf(T[q2][ds + 2 * i]) |
                  ((uint)f2bf(T[q2][ds + 2 * i + 1]) << 16);
    ushort* dst = oh + ((size_t)b * S_LEN + qt * 64 + q2) * 64 + ds;
    uint4 o1, o2;
    o1.x = wbuf[0]; o1.y = wbuf[1]; o1.z = wbuf[2]; o1.w = wbuf[3];
    o2.x = wbuf[4]; o2.y = wbuf[5]; o2.z = wbuf[6]; o2.w = wbuf[7];
    *reinterpret_cast<uint4*>(dst)     = o1;
    *reinterpret_cast<uint4*>(dst + 8) = o2;
}

// ---------------------------------------------------------------------------
// Epilogue (MFMA): out[8192,1024] = oh[8192,64] @ WoT^T.  Grid (128, 8).
// ---------------------------------------------------------------------------
__global__ __launch_bounds__(256) void epilogue_mfma(
    const ushort* __restrict__ oh, const ushort* __restrict__ WoT,
    float* __restrict__ out)
{
    const int r0 = blockIdx.x * 64;
    const int c0 = blockIdx.y * 128;
    __shared__ ushort As[64][72];
    __shared__ ushort Bs[128][72];

    const int t    = threadIdx.x;
    const int w    = t >> 6;
    const int lane = t & 63;
    const int lg   = lane >> 4;
    const int lc   = lane & 15;

    #pragma unroll
    for (int q = 0; q < 2; ++q) {
        int u   = t * 2 + q;
        int row = u >> 3;
        int c8  = (u & 7) << 3;
        *reinterpret_cast<uint4*>(&As[row][c8]) =
            *reinterpret_cast<const uint4*>(oh + (size_t)(r0 + row) * 64 + c8);
    }
    #pragma unroll
    for (int q = 0; q < 4; ++q) {
        int u   = t * 4 + q;
        int row = u >> 3;
        int c8  = (u & 7) << 3;
        *reinterpret_cast<uint4*>(&Bs[row][c8]) =
            *reinterpret_cast<const uint4*>(WoT + (size_t)(c0 + row) * 64 + c8);
    }
    __syncthreads();

    bf16x8 af0 = *reinterpret_cast<const bf16x8*>(&As[16 * w + lc][lg * 8]);
    bf16x8 af1 = *reinterpret_cast<const bf16x8*>(&As[16 * w + lc][32 + lg * 8]);
    f32x4 acc[8] = {};
    #pragma unroll
    for (int n = 0; n < 8; ++n) {
        bf16x8 bf0 = *reinterpret_cast<const bf16x8*>(&Bs[16 * n + lc][lg * 8]);
        bf16x8 bf1 = *reinterpret_cast<const bf16x8*>(&Bs[16 * n + lc][32 + lg * 8]);
        acc[n] = __builtin_amdgcn_mfma_f32_16x16x32_bf16(af0, bf0, acc[n], 0, 0, 0);
        acc[n] = __builtin_amdgcn_mfma_f32_16x16x32_bf16(af1, bf1, acc[n], 0, 0, 0);
    }
    #pragma unroll
    for (int n = 0; n < 8; ++n)
        #pragma unroll
        for (int reg = 0; reg < 4; ++reg)
            out[(size_t)(r0 + 16 * w + 4 * lg + reg) * 1024 + c0 + 16 * n + lc] =
                acc[n][reg];
}

// ---------------------------------------------------------------------------
extern "C" void kernel_launch(void* const* d_in, const int* in_sizes, int n_in,
                              void* d_out, int out_size, void* d_ws, size_t ws_size,
                              hipStream_t stream)
{
    const float* query = (const float*)d_in[0];
    const float* key   = (const float*)d_in[1];
    const float* value = (const float*)d_in[2];
    const float* Wq   = (const float*)d_in[4];
    const float* Wk   = (const float*)d_in[5];
    const float* Wv   = (const float*)d_in[6];
    const float* wq_h = (const float*)d_in[7];
    const float* bq_h = (const float*)d_in[8];
    const float* wk_h = (const float*)d_in[9];
    const float* bk_h = (const float*)d_in[10];
    const float* wv_h = (const float*)d_in[11];
    const float* bv_h = (const float*)d_in[12];
    const float* Wo   = (const float*)d_in[13];
    float* out = (float*)d_out;

    // workspace (ushort units): ~6.2 MB
    ushort* W16  = (ushort*)d_ws;
    ushort* WT0  = W16;                 // 64*1024 each
    ushort* WT1  = W16 + 65536;
    ushort* WT2  = W16 + 131072;
    ushort* WoT  = W16 + 196608;        // 1024*64
    ushort* qh   = W16 + 262144;        // 8192*64 each
    ushort* kh   = qh + 524288;
    ushort* vh   = kh + 524288;
    ushort* vhT  = vh + 524288;
    ushort* oh   = vhT + 524288;
    ushort* whT0 = oh + 524288;         // 64*1024 each
    ushort* whT1 = whT0 + 65536;
    ushort* whT2 = whT1 + 65536;

    // flash partials in d_out (9.7 MB < 33.5 MB); epilogue rewrites all of it.
    float* Opart = out;                 // 576 * 4096
    float* mpart = out + 2359296;       // 576 * 64
    float* lpart = out + 2396160;

    transpose_wh<<<dim3(16, 3), 256, 0, stream>>>(
        wq_h, wk_h, wv_h, whT0, whT1, whT2);
    fold_wo<<<256, 256, 0, stream>>>(Wo, WoT);

    prep_direct<<<dim3(64, 3), 256, 0, stream>>>(
        Wq, Wk, Wv, whT0, whT1, whT2, WT0, WT1, WT2);

    proj_direct<<<dim3(512, 3), 256, 0, stream>>>(
        query, key, value, WT0, WT1, WT2, bq_h, bk_h, bv_h, qh, kh, vh);

    transpose_v<<<dim3(S_LEN / 64, BATCH), 256, 0, stream>>>(vh, vhT);

    flash_mfma<<<dim3(144, BATCH), 256, 0, stream>>>(
        qh, kh, vhT, Opart, mpart, lpart);
    flash_combine<<<dim3(S_LEN / 64, BATCH), 256, 0, stream>>>(
        Opart, mpart, lpart, oh);

    epilogue_mfma<<<dim3(NROWS / 64, DMODEL / 128), 256, 0, stream>>>(oh, WoT, out);
}

// Round 9
// 83.161 us; speedup vs baseline: 1.0246x; 1.0048x over previous
//
#include <hip/hip_runtime.h>
#include <math.h>

#define S_LEN 2048
#define BATCH 4
#define DMODEL 1024
#define HDIM 64
#define NROWS (BATCH * S_LEN)   // 8192

typedef __attribute__((ext_vector_type(8))) short bf16x8;
typedef __attribute__((ext_vector_type(4))) float f32x4;

#define GLP(p) ((const __attribute__((address_space(1))) unsigned int*)(p))
#define LDP(p) ((__attribute__((address_space(3))) unsigned int*)(p))

__device__ inline ushort f2bf(float f) {
    union { float f; uint u; } v{f};
    uint r = v.u + 0x7fffu + ((v.u >> 16) & 1u);   // RNE
    return (ushort)(r >> 16);
}

__device__ inline bf16x8 cvt8(float4 a, float4 b) {
    bf16x8 r;
    r[0] = (short)f2bf(a.x); r[1] = (short)f2bf(a.y);
    r[2] = (short)f2bf(a.z); r[3] = (short)f2bf(a.w);
    r[4] = (short)f2bf(b.x); r[5] = (short)f2bf(b.y);
    r[6] = (short)f2bf(b.z); r[7] = (short)f2bf(b.w);
    return r;
}

// ---------------------------------------------------------------------------
// transpose_wh: w_h f32 [1024][64] -> whT bf16 [64][1024].  Grid (16, 3).
// ---------------------------------------------------------------------------
__global__ __launch_bounds__(256) void transpose_wh(
    const float* __restrict__ B0, const float* __restrict__ B1, const float* __restrict__ B2,
    ushort* __restrict__ T0, ushort* __restrict__ T1, ushort* __restrict__ T2)
{
    const int z = blockIdx.y;
    const float* B = (z == 0) ? B0 : (z == 1) ? B1 : B2;
    ushort* T      = (z == 0) ? T0 : (z == 1) ? T1 : T2;
    const int kr0 = blockIdx.x * 64;
    __shared__ ushort Ts[64][72];
    const int t = threadIdx.x;

    #pragma unroll
    for (int q = 0; q < 4; ++q) {
        int u   = t * 4 + q;
        int row = u >> 4;
        int c4  = (u & 15) << 2;
        float4 v = *reinterpret_cast<const float4*>(
            B + (size_t)(kr0 + row) * 64 + c4);
        Ts[row][c4 + 0] = f2bf(v.x); Ts[row][c4 + 1] = f2bf(v.y);
        Ts[row][c4 + 2] = f2bf(v.z); Ts[row][c4 + 3] = f2bf(v.w);
    }
    __syncthreads();
    #pragma unroll
    for (int q = 0; q < 2; ++q) {
        int u  = t * 2 + q;
        int h  = u >> 3;
        int k8 = (u & 7) << 3;
        uint4 o;
        uint* ow = reinterpret_cast<uint*>(&o);
        #pragma unroll
        for (int i = 0; i < 4; ++i)
            ow[i] = (uint)Ts[k8 + 2 * i][h] | ((uint)Ts[k8 + 2 * i + 1][h] << 16);
        *reinterpret_cast<uint4*>(T + (size_t)h * 1024 + kr0 + k8) = o;
    }
}

// ---------------------------------------------------------------------------
// prep_direct: WeffT_z[h][d] = (W_z @ w_h_z)^T bf16.  Grid (64, 3).
// (round-8 version, validated; small data so latency acceptable)
// ---------------------------------------------------------------------------
__global__ __launch_bounds__(256) void prep_direct(
    const float* __restrict__ A0, const float* __restrict__ A1, const float* __restrict__ A2,
    const ushort* __restrict__ W0, const ushort* __restrict__ W1, const ushort* __restrict__ W2,
    ushort* __restrict__ T0, ushort* __restrict__ T1, ushort* __restrict__ T2)
{
    const int z = blockIdx.y;
    const float* A  = (z == 0) ? A0 : (z == 1) ? A1 : A2;
    const ushort* W = (z == 0) ? W0 : (z == 1) ? W1 : W2;
    ushort* T       = (z == 0) ? T0 : (z == 1) ? T1 : T2;

    __shared__ float Pr[4][16][64];

    const int t    = threadIdx.x;
    const int w    = t >> 6;
    const int lane = t & 63;
    const int lg   = lane >> 4;
    const int lc   = lane & 15;
    const int r0   = blockIdx.x * 16;

    const float*  Ap = A + (size_t)(r0 + lc) * 1024 + (w << 8) + (lg << 3);
    const ushort* Bp = W + (size_t)lc * 1024 + (w << 8) + (lg << 3);

    f32x4 acc[4] = {};
    float4 a0[2], a1[2];
    uint4  bl[2][4];

    #pragma unroll
    for (int d = 0; d < 2; ++d) {
        a0[d] = *reinterpret_cast<const float4*>(Ap + d * 32);
        a1[d] = *reinterpret_cast<const float4*>(Ap + d * 32 + 4);
        #pragma unroll
        for (int n = 0; n < 4; ++n)
            bl[d][n] = *reinterpret_cast<const uint4*>(Bp + n * 16384 + d * 32);
    }

    #pragma unroll
    for (int ks = 0; ks < 8; ++ks) {
        const int d = ks & 1;
        bf16x8 af = cvt8(a0[d], a1[d]);
        bf16x8 bfr[4];
        #pragma unroll
        for (int n = 0; n < 4; ++n)
            bfr[n] = __builtin_bit_cast(bf16x8, bl[d][n]);
        if (ks < 6) {
            a0[d] = *reinterpret_cast<const float4*>(Ap + (ks + 2) * 32);
            a1[d] = *reinterpret_cast<const float4*>(Ap + (ks + 2) * 32 + 4);
            #pragma unroll
            for (int n = 0; n < 4; ++n)
                bl[d][n] = *reinterpret_cast<const uint4*>(Bp + n * 16384 + (ks + 2) * 32);
        }
        #pragma unroll
        for (int n = 0; n < 4; ++n)
            acc[n] = __builtin_amdgcn_mfma_f32_16x16x32_bf16(af, bfr[n], acc[n], 0, 0, 0);
    }

    #pragma unroll
    for (int n = 0; n < 4; ++n)
        #pragma unroll
        for (int reg = 0; reg < 4; ++reg)
            Pr[w][4 * lg + reg][16 * n + lc] = acc[n][reg];
    __syncthreads();

    const int row = t >> 4;
    const int col = (t & 15) << 2;
    float s[4];
    #pragma unroll
    for (int i = 0; i < 4; ++i)
        s[i] = Pr[0][row][col + i] + Pr[1][row][col + i] +
               Pr[2][row][col + i] + Pr[3][row][col + i];
    #pragma unroll
    for (int i = 0; i < 4; ++i)
        T[(size_t)(col + i) * 1024 + r0 + row] = f2bf(s[i]);
}

// ---------------------------------------------------------------------------
// proj_stream: ph_z[8192,64] = bf16(x_z @ WeffT_z^T + bias).  Grid (512, 3).
// Block = 16 rows, 4 waves; wave w owns k in [256w, 256w+256) as 4 chunks of
// 64 k.  Per wave: preload all B-frags to regs (drain vmcnt once), then issue
// ALL 16 global_load_lds (wave-private LDS, XOR-swizzled source), then
// consume chunk c after s_waitcnt vmcnt((3-c)*4)  [T3/T4, wave-scoped, no
// barrier in the K-loop].  Cross-wave LDS reduce at the end.
// ---------------------------------------------------------------------------
__global__ __launch_bounds__(256) void proj_stream(
    const float* __restrict__ A0, const float* __restrict__ A1, const float* __restrict__ A2,
    const ushort* __restrict__ W0, const ushort* __restrict__ W1, const ushort* __restrict__ W2,
    const float* __restrict__ b0, const float* __restrict__ b1, const float* __restrict__ b2,
    ushort* __restrict__ O0, ushort* __restrict__ O1, ushort* __restrict__ O2)
{
    const int z = blockIdx.y;
    const float* A    = (z == 0) ? A0 : (z == 1) ? A1 : A2;
    const ushort* W   = (z == 0) ? W0 : (z == 1) ? W1 : W2;
    const float* bias = (z == 0) ? b0 : (z == 1) ? b1 : b2;
    ushort* O         = (z == 0) ? O0 : (z == 1) ? O1 : O2;

    __shared__ __align__(16) char StageRaw[65536];   // 4 waves x 16 KB
    __shared__ float Pr[4][16][64];                  // 16 KB reduce buffer

    const int t    = threadIdx.x;
    const int w    = t >> 6;
    const int lane = t & 63;
    const int lg   = lane >> 4;
    const int lc   = lane & 15;
    const int rx   = lc & 7;
    const int r0   = blockIdx.x * 16;

    // ---- preload all B fragments (WeffT is L2-resident) ----
    bf16x8 bB[4][4][2];
    #pragma unroll
    for (int c = 0; c < 4; ++c)
        #pragma unroll
        for (int n = 0; n < 4; ++n)
            #pragma unroll
            for (int h = 0; h < 2; ++h)
                bB[c][n][h] = *reinterpret_cast<const bf16x8*>(
                    W + (size_t)(16 * n + lc) * 1024 + (w << 8) + (c << 6) +
                    h * 32 + lg * 8);
    // drain: all subsequent vmcnt counts are purely the A stages below
    asm volatile("s_waitcnt vmcnt(0)" ::: "memory");
    __builtin_amdgcn_sched_barrier(0);

    // ---- issue all 16 A stage loads (4 chunks x 4 insts, 1 KB each) ----
    // LDS layout per wave/chunk: [16 rows][16 units of 16B], unit pos holds
    // global k-unit g = (pos&8) | ((pos&7) ^ (row&7))   (XOR swizzle, T2/21)
    #pragma unroll
    for (int c = 0; c < 4; ++c)
        #pragma unroll
        for (int p = 0; p < 4; ++p) {
            int u   = p * 64 + lane;
            int row = u >> 4;
            int pos = u & 15;
            int g   = (pos & 8) | ((pos & 7) ^ (row & 7));
            __builtin_amdgcn_global_load_lds(
                GLP(A + (size_t)(r0 + row) * 1024 + (w << 8) + (c << 6) + g * 4),
                LDP(StageRaw + (size_t)w * 16384 + c * 4096 + p * 1024),
                16, 0, 0);
        }

    f32x4 acc[4] = {};
    const float4* lpw = reinterpret_cast<const float4*>(
        StageRaw + (size_t)w * 16384);

#define PROJ_CHUNK(c, VM)                                                     \
    {                                                                         \
        asm volatile("s_waitcnt vmcnt(" #VM ")" ::: "memory");                \
        __builtin_amdgcn_sched_barrier(0);                                    \
        const float4* lp = lpw + (c) * 256 + lc * 16;                         \
        float4 f0 = lp[( (lg * 2 + 0) ^ rx)];                                 \
        float4 f1 = lp[( (lg * 2 + 1) ^ rx)];                                 \
        float4 f2 = lp[(8 | ((lg * 2 + 0) ^ rx))];                            \
        float4 f3 = lp[(8 | ((lg * 2 + 1) ^ rx))];                            \
        bf16x8 a0 = cvt8(f0, f1);                                             \
        bf16x8 a1 = cvt8(f2, f3);                                             \
        acc[0] = __builtin_amdgcn_mfma_f32_16x16x32_bf16(a0, bB[c][0][0], acc[0], 0, 0, 0); \
        acc[0] = __builtin_amdgcn_mfma_f32_16x16x32_bf16(a1, bB[c][0][1], acc[0], 0, 0, 0); \
        acc[1] = __builtin_amdgcn_mfma_f32_16x16x32_bf16(a0, bB[c][1][0], acc[1], 0, 0, 0); \
        acc[1] = __builtin_amdgcn_mfma_f32_16x16x32_bf16(a1, bB[c][1][1], acc[1], 0, 0, 0); \
        acc[2] = __builtin_amdgcn_mfma_f32_16x16x32_bf16(a0, bB[c][2][0], acc[2], 0, 0, 0); \
        acc[2] = __builtin_amdgcn_mfma_f32_16x16x32_bf16(a1, bB[c][2][1], acc[2], 0, 0, 0); \
        acc[3] = __builtin_amdgcn_mfma_f32_16x16x32_bf16(a0, bB[c][3][0], acc[3], 0, 0, 0); \
        acc[3] = __builtin_amdgcn_mfma_f32_16x16x32_bf16(a1, bB[c][3][1], acc[3], 0, 0, 0); \
    }

    PROJ_CHUNK(0, 12)
    PROJ_CHUNK(1, 8)
    PROJ_CHUNK(2, 4)
    PROJ_CHUNK(3, 0)
#undef PROJ_CHUNK

    // ---- cross-wave reduce + bias + store ----
    #pragma unroll
    for (int n = 0; n < 4; ++n)
        #pragma unroll
        for (int reg = 0; reg < 4; ++reg)
            Pr[w][4 * lg + reg][16 * n + lc] = acc[n][reg];
    __syncthreads();

    const int row = t >> 4;
    const int col = (t & 15) << 2;
    float4 bb = *reinterpret_cast<const float4*>(bias + col);
    float s0 = Pr[0][row][col + 0] + Pr[1][row][col + 0] + Pr[2][row][col + 0] + Pr[3][row][col + 0] + bb.x;
    float s1 = Pr[0][row][col + 1] + Pr[1][row][col + 1] + Pr[2][row][col + 1] + Pr[3][row][col + 1] + bb.y;
    float s2 = Pr[0][row][col + 2] + Pr[1][row][col + 2] + Pr[2][row][col + 2] + Pr[3][row][col + 2] + bb.z;
    float s3 = Pr[0][row][col + 3] + Pr[1][row][col + 3] + Pr[2][row][col + 3] + Pr[3][row][col + 3] + bb.w;
    ushort4 o;
    o.x = f2bf(s0); o.y = f2bf(s1); o.z = f2bf(s2); o.w = f2bf(s3);
    *reinterpret_cast<ushort4*>(O + (size_t)(r0 + row) * 64 + col) = o;
}

// ---------------------------------------------------------------------------
// Prep 2: WoT[e][j] = sum_h Wo[h*64+j][e]  -> bf16 [1024][64]
// ---------------------------------------------------------------------------
__global__ __launch_bounds__(256) void fold_wo(const float* __restrict__ Wo,
                                               ushort* __restrict__ WoT)
{
    int idx = blockIdx.x * 256 + threadIdx.x;
    int j = idx >> 10;
    int e = idx & 1023;
    float s = 0.f;
    #pragma unroll
    for (int h = 0; h < 16; ++h)
        s += Wo[(size_t)((h << 6) + j) * 1024 + e];
    WoT[(size_t)e * 64 + j] = f2bf(s);
}

// ---------------------------------------------------------------------------
// V transpose: vh[b][s][64] bf16 -> vhT[b][64][2048] bf16.  Grid (32, 4).
// ---------------------------------------------------------------------------
__global__ __launch_bounds__(256) void transpose_v(const ushort* __restrict__ vh,
                                                   ushort* __restrict__ vhT)
{
    const int b  = blockIdx.y;
    const int r0 = blockIdx.x * 64;
    __shared__ ushort T[64][72];
    const int t = threadIdx.x;

    #pragma unroll
    for (int q = 0; q < 2; ++q) {
        int u  = t * 2 + q;
        int s  = u >> 3;
        int d8 = (u & 7) << 3;
        uint4 v = *reinterpret_cast<const uint4*>(
            vh + ((size_t)b * S_LEN + r0 + s) * 64 + d8);
        *reinterpret_cast<uint4*>(&T[s][d8]) = v;
    }
    __syncthreads();
    #pragma unroll
    for (int q = 0; q < 2; ++q) {
        int u  = t * 2 + q;
        int d  = u >> 3;
        int s8 = (u & 7) << 3;
        uint4 o;
        uint* ow = reinterpret_cast<uint*>(&o);
        #pragma unroll
        for (int i = 0; i < 4; ++i)
            ow[i] = (uint)T[s8 + 2 * i][d] | ((uint)T[s8 + 2 * i + 1][d] << 16);
        *reinterpret_cast<uint4*>(
            vhT + (size_t)b * 64 * S_LEN + (size_t)d * S_LEN + r0 + s8) = o;
    }
}

// ---------------------------------------------------------------------------
// Flash attention (MFMA, split-KV): block = 64 q-rows x 256-kv chunk.
// Grid (144, 4).
// ---------------------------------------------------------------------------
__global__ __launch_bounds__(256) void flash_mfma(
    const ushort* __restrict__ qh, const ushort* __restrict__ kh,
    const ushort* __restrict__ vhT,
    float* __restrict__ Opart, float* __restrict__ mpart, float* __restrict__ lpart)
{
    const int b = blockIdx.y;
    const int u = blockIdx.x;
    int gi = 0;
    #pragma unroll
    for (int gg = 0; gg < 7; ++gg)
        if (u >= 2 * (gg + 1) * (gg + 2)) gi = gg + 1;
    const int rem = u - 2 * gi * (gi + 1);
    const int dq  = rem / (gi + 1);
    const int c   = rem - dq * (gi + 1);
    const int qt  = 4 * gi + dq;
    const int r0  = qt * 64;
    const int kvbase = c << 8;
    const int slot = b * 144 + u;

    __shared__ ushort Qs[64][72];
    __shared__ ushort Ks[64][72];
    __shared__ ushort Vt[64][72];
    __shared__ ushort Pw[4][16][72];

    const int t    = threadIdx.x;
    const int w    = t >> 6;
    const int lane = t & 63;
    const int lg   = lane >> 4;
    const int lc   = lane & 15;

    const ushort* qb  = qh  + (size_t)b * S_LEN * 64;
    const ushort* kb  = kh  + (size_t)b * S_LEN * 64;
    const ushort* vtb = vhT + (size_t)b * 64 * S_LEN;

    #pragma unroll
    for (int q = 0; q < 2; ++q) {
        int uu  = t * 2 + q;
        int row = uu >> 3;
        int c8  = (uu & 7) << 3;
        *reinterpret_cast<uint4*>(&Qs[row][c8]) =
            *reinterpret_cast<const uint4*>(qb + (size_t)(r0 + row) * 64 + c8);
    }
    __syncthreads();
    bf16x8 qf0 = *reinterpret_cast<const bf16x8*>(&Qs[16 * w + lc][lg * 8]);
    bf16x8 qf1 = *reinterpret_cast<const bf16x8*>(&Qs[16 * w + lc][32 + lg * 8]);

    f32x4 od[4] = {};
    float m = -INFINITY, lsum = 0.f;
    const int qrow = r0 + 16 * w + lc;

    const int ntt = min(4, ((r0 + 63 - kvbase) >> 6) + 1);
    for (int tt = 0; tt < ntt; ++tt) {
        const int t0 = kvbase + (tt << 6);
        __syncthreads();
        #pragma unroll
        for (int q = 0; q < 2; ++q) {
            int uu  = t * 2 + q;
            int row = uu >> 3;
            int c8  = (uu & 7) << 3;
            *reinterpret_cast<uint4*>(&Ks[row][c8]) =
                *reinterpret_cast<const uint4*>(kb + (size_t)(t0 + row) * 64 + c8);
            *reinterpret_cast<uint4*>(&Vt[row][c8]) =
                *reinterpret_cast<const uint4*>(vtb + (size_t)row * S_LEN + t0 + c8);
        }
        __syncthreads();

        if (t0 <= r0 + 16 * w + 15) {
            f32x4 s[4] = {};
            #pragma unroll
            for (int a = 0; a < 4; ++a) {
                bf16x8 kf0 = *reinterpret_cast<const bf16x8*>(&Ks[16 * a + lc][lg * 8]);
                bf16x8 kf1 = *reinterpret_cast<const bf16x8*>(&Ks[16 * a + lc][32 + lg * 8]);
                s[a] = __builtin_amdgcn_mfma_f32_16x16x32_bf16(kf0, qf0, s[a], 0, 0, 0);
                s[a] = __builtin_amdgcn_mfma_f32_16x16x32_bf16(kf1, qf1, s[a], 0, 0, 0);
            }
            float rm = -1e30f;
            #pragma unroll
            for (int a = 0; a < 4; ++a)
                #pragma unroll
                for (int reg = 0; reg < 4; ++reg) {
                    int kv = t0 + 16 * a + 4 * lg + reg;
                    float v = s[a][reg] * 0.125f;
                    if (kv > qrow) v = -1e30f;
                    s[a][reg] = v;
                    rm = fmaxf(rm, v);
                }
            rm = fmaxf(rm, __shfl_xor(rm, 16));
            rm = fmaxf(rm, __shfl_xor(rm, 32));
            float mn = fmaxf(m, rm);
            float sc = __expf(m - mn);
            float rs = 0.f;
            #pragma unroll
            for (int a = 0; a < 4; ++a)
                #pragma unroll
                for (int reg = 0; reg < 4; ++reg) {
                    float p = __expf(s[a][reg] - mn);
                    s[a][reg] = p;
                    rs += p;
                }
            rs += __shfl_xor(rs, 16);
            rs += __shfl_xor(rs, 32);
            lsum = lsum * sc + rs;
            m = mn;
            #pragma unroll
            for (int di = 0; di < 4; ++di) od[di] *= sc;

            #pragma unroll
            for (int a = 0; a < 4; ++a)
                #pragma unroll
                for (int rp = 0; rp < 2; ++rp) {
                    uint pk = (uint)f2bf(s[a][2 * rp]) |
                              ((uint)f2bf(s[a][2 * rp + 1]) << 16);
                    *reinterpret_cast<uint*>(&Pw[w][lc][16 * a + 4 * lg + 2 * rp]) = pk;
                }
            bf16x8 pf0 = *reinterpret_cast<const bf16x8*>(&Pw[w][lc][lg * 8]);
            bf16x8 pf1 = *reinterpret_cast<const bf16x8*>(&Pw[w][lc][32 + lg * 8]);
            #pragma unroll
            for (int di = 0; di < 4; ++di) {
                bf16x8 vf0 = *reinterpret_cast<const bf16x8*>(&Vt[16 * di + lc][lg * 8]);
                bf16x8 vf1 = *reinterpret_cast<const bf16x8*>(&Vt[16 * di + lc][32 + lg * 8]);
                od[di] = __builtin_amdgcn_mfma_f32_16x16x32_bf16(vf0, pf0, od[di], 0, 0, 0);
                od[di] = __builtin_amdgcn_mfma_f32_16x16x32_bf16(vf1, pf1, od[di], 0, 0, 0);
            }
        }
    }

    #pragma unroll
    for (int di = 0; di < 4; ++di)
        #pragma unroll
        for (int reg = 0; reg < 4; ++reg)
            Opart[(size_t)slot * 4096 + (16 * di + 4 * lg + reg) * 64 + 16 * w + lc] =
                od[di][reg];
    if (lg == 0) {
        mpart[slot * 64 + 16 * w + lc] = m;
        lpart[slot * 64 + 16 * w + lc] = lsum;
    }
}

// ---------------------------------------------------------------------------
// Combine partials -> oh bf16 [8192][64].  Grid (32, 4), 256 threads.
// ---------------------------------------------------------------------------
__global__ __launch_bounds__(256) void flash_combine(
    const float* __restrict__ Opart, const float* __restrict__ mpart,
    const float* __restrict__ lpart, ushort* __restrict__ oh)
{
    const int qt = blockIdx.x, b = blockIdx.y;
    const int gi = qt >> 2;
    const int nc = gi + 1;
    const int ubase = 2 * gi * (gi + 1) + (qt & 3) * (gi + 1);
    __shared__ float T[64][65];

    const int t  = threadIdx.x;
    const int q  = t & 63;
    const int d0 = (t >> 6) << 4;

    float mc[8];
    float M = -INFINITY;
    #pragma unroll
    for (int cc = 0; cc < 8; ++cc) {
        mc[cc] = (cc < nc) ? mpart[(b * 144 + ubase + cc) * 64 + q] : -INFINITY;
        M = fmaxf(M, mc[cc]);
    }
    float L = 0.f;
    float acc[16] = {};
    for (int cc = 0; cc < nc; ++cc) {
        const int slot = b * 144 + ubase + cc;
        float wgt = __expf(mc[cc] - M);
        L += lpart[slot * 64 + q] * wgt;
        const float* op = Opart + (size_t)slot * 4096 + q;
        #pragma unroll
        for (int i = 0; i < 16; ++i)
            acc[i] += wgt * op[(d0 + i) * 64];
    }
    float inv = 1.f / L;
    #pragma unroll
    for (int i = 0; i < 16; ++i) T[q][d0 + i] = acc[i] * inv;
    __syncthreads();

    const int q2 = t >> 2;
    const int ds = (t & 3) << 4;
    uint wbuf[8];
    #pragma unroll
    for (int i = 0; i < 8; ++i)
        wbuf[i] = (uint)f2bf(T[q2][ds + 2 * i]) |
                  ((uint)f2bf(T[q2][ds + 2 * i + 1]) << 16);
    ushort* dst = oh + ((size_t)b * S_LEN + qt * 64 + q2) * 64 + ds;
    uint4 o1, o2;
    o1.x = wbuf[0]; o1.y = wbuf[1]; o1.z = wbuf[2]; o1.w = wbuf[3];
    o2.x = wbuf[4]; o2.y = wbuf[5]; o2.z = wbuf[6]; o2.w = wbuf[7];
    *reinterpret_cast<uint4*>(dst)     = o1;
    *reinterpret_cast<uint4*>(dst + 8) = o2;
}

// ---------------------------------------------------------------------------
// Epilogue (MFMA): out[8192,1024] = oh[8192,64] @ WoT^T.  Grid (128, 8).
// ---------------------------------------------------------------------------
__global__ __launch_bounds__(256) void epilogue_mfma(
    const ushort* __restrict__ oh, const ushort* __restrict__ WoT,
    float* __restrict__ out)
{
    const int r0 = blockIdx.x * 64;
    const int c0 = blockIdx.y * 128;
    __shared__ ushort As[64][72];
    __shared__ ushort Bs[128][72];

    const int t    = threadIdx.x;
    const int w    = t >> 6;
    const int lane = t & 63;
    const int lg   = lane >> 4;
    const int lc   = lane & 15;

    #pragma unroll
    for (int q = 0; q < 2; ++q) {
        int u   = t * 2 + q;
        int row = u >> 3;
        int c8  = (u & 7) << 3;
        *reinterpret_cast<uint4*>(&As[row][c8]) =
            *reinterpret_cast<const uint4*>(oh + (size_t)(r0 + row) * 64 + c8);
    }
    #pragma unroll
    for (int q = 0; q < 4; ++q) {
        int u   = t * 4 + q;
        int row = u >> 3;
        int c8  = (u & 7) << 3;
        *reinterpret_cast<uint4*>(&Bs[row][c8]) =
            *reinterpret_cast<const uint4*>(WoT + (size_t)(c0 + row) * 64 + c8);
    }
    __syncthreads();

    bf16x8 af0 = *reinterpret_cast<const bf16x8*>(&As[16 * w + lc][lg * 8]);
    bf16x8 af1 = *reinterpret_cast<const bf16x8*>(&As[16 * w + lc][32 + lg * 8]);
    f32x4 acc[8] = {};
    #pragma unroll
    for (int n = 0; n < 8; ++n) {
        bf16x8 bf0 = *reinterpret_cast<const bf16x8*>(&Bs[16 * n + lc][lg * 8]);
        bf16x8 bf1 = *reinterpret_cast<const bf16x8*>(&Bs[16 * n + lc][32 + lg * 8]);
        acc[n] = __builtin_amdgcn_mfma_f32_16x16x32_bf16(af0, bf0, acc[n], 0, 0, 0);
        acc[n] = __builtin_amdgcn_mfma_f32_16x16x32_bf16(af1, bf1, acc[n], 0, 0, 0);
    }
    #pragma unroll
    for (int n = 0; n < 8; ++n)
        #pragma unroll
        for (int reg = 0; reg < 4; ++reg)
            out[(size_t)(r0 + 16 * w + 4 * lg + reg) * 1024 + c0 + 16 * n + lc] =
                acc[n][reg];
}

// ---------------------------------------------------------------------------
extern "C" void kernel_launch(void* const* d_in, const int* in_sizes, int n_in,
                              void* d_out, int out_size, void* d_ws, size_t ws_size,
                              hipStream_t stream)
{
    const float* query = (const float*)d_in[0];
    const float* key   = (const float*)d_in[1];
    const float* value = (const float*)d_in[2];
    const float* Wq   = (const float*)d_in[4];
    const float* Wk   = (const float*)d_in[5];
    const float* Wv   = (const float*)d_in[6];
    const float* wq_h = (const float*)d_in[7];
    const float* bq_h = (const float*)d_in[8];
    const float* wk_h = (const float*)d_in[9];
    const float* bk_h = (const float*)d_in[10];
    const float* wv_h = (const float*)d_in[11];
    const float* bv_h = (const float*)d_in[12];
    const float* Wo   = (const float*)d_in[13];
    float* out = (float*)d_out;

    // workspace (ushort units): ~6.2 MB
    ushort* W16  = (ushort*)d_ws;
    ushort* WT0  = W16;                 // 64*1024 each
    ushort* WT1  = W16 + 65536;
    ushort* WT2  = W16 + 131072;
    ushort* WoT  = W16 + 196608;        // 1024*64
    ushort* qh   = W16 + 262144;        // 8192*64 each
    ushort* kh   = qh + 524288;
    ushort* vh   = kh + 524288;
    ushort* vhT  = vh + 524288;
    ushort* oh   = vhT + 524288;
    ushort* whT0 = oh + 524288;         // 64*1024 each
    ushort* whT1 = whT0 + 65536;
    ushort* whT2 = whT1 + 65536;

    // flash partials in d_out (9.7 MB < 33.5 MB); epilogue rewrites all of it.
    float* Opart = out;                 // 576 * 4096
    float* mpart = out + 2359296;       // 576 * 64
    float* lpart = out + 2396160;

    transpose_wh<<<dim3(16, 3), 256, 0, stream>>>(
        wq_h, wk_h, wv_h, whT0, whT1, whT2);
    fold_wo<<<256, 256, 0, stream>>>(Wo, WoT);

    prep_direct<<<dim3(64, 3), 256, 0, stream>>>(
        Wq, Wk, Wv, whT0, whT1, whT2, WT0, WT1, WT2);

    proj_stream<<<dim3(512, 3), 256, 0, stream>>>(
        query, key, value, WT0, WT1, WT2, bq_h, bk_h, bv_h, qh, kh, vh);

    transpose_v<<<dim3(S_LEN / 64, BATCH), 256, 0, stream>>>(vh, vhT);

    flash_mfma<<<dim3(144, BATCH), 256, 0, stream>>>(
        qh, kh, vhT, Opart, mpart, lpart);
    flash_combine<<<dim3(S_LEN / 64, BATCH), 256, 0, stream>>>(
        Opart, mpart, lpart, oh);

    epilogue_mfma<<<dim3(NROWS / 64, DMODEL / 128), 256, 0, stream>>>(oh, WoT, out);
}